// Round 8
// baseline (490.076 us; speedup 1.0000x reference)
//
#include <hip/hip_runtime.h>
#include <hip/hip_bf16.h>
#include <math.h>

#define BLK 64
#define EPB 16            // elements per block (one wave)
#define NF 32
#define THIST 15
#define HXS 18            // hx row stride in u32: reads 2-way max (free)

typedef __attribute__((ext_vector_type(8))) short s16x8;  // 8 bf16 = 4 VGPRs
typedef __attribute__((ext_vector_type(4))) float f32x4;

union frag_u { s16x8 v; unsigned u[4]; };

__device__ __forceinline__ float sigm(float x) {
    return __fdividef(1.0f, 1.0f + __expf(-x));
}
// tanh = 1 - 2/(e^{2x}+1); exact saturation, no abs/copysign
__device__ __forceinline__ float tanhfe(float x) {
    float e = __expf(2.0f * x);
    return 1.0f - __fdividef(2.0f, e + 1.0f);
}
__device__ __forceinline__ float bf16tof(unsigned short h) {
    return __uint_as_float(((unsigned)h) << 16);
}
__device__ __forceinline__ unsigned packbf2(float x0, float x1) {
    __hip_bfloat162 b = __float22bfloat162_rn(float2{x0, x1});
    union { __hip_bfloat162 b; unsigned u; } c; c.b = b; return c.u;
}
// split a PAIR of fp32 into packed-hi / packed-lo bf16 dwords (RNE, ~17-bit eff.)
__device__ __forceinline__ void bsplit2(float x0, float x1, unsigned& h2, unsigned& l2) {
    h2 = packbf2(x0, x1);
    float r0 = x0 - bf16tof((unsigned short)(h2 & 0xffffu));
    float r1 = x1 - bf16tof((unsigned short)(h2 >> 16));
    l2 = packbf2(r0, r1);
}

// P = F P F^T for the constant-accel F (dt=0.2), in place
__device__ __forceinline__ void fpft(float (&P)[6][6]) {
    const float dt = 0.2f, hd = 0.02f;
    #pragma unroll
    for (int j = 0; j < 6; ++j) {
        float a0 = P[0][j] + dt * P[1][j] + hd * P[2][j];
        float a1 = P[1][j] + dt * P[2][j];
        float a3 = P[3][j] + dt * P[4][j] + hd * P[5][j];
        float a4 = P[4][j] + dt * P[5][j];
        P[0][j] = a0; P[1][j] = a1; P[3][j] = a3; P[4][j] = a4;
    }
    #pragma unroll
    for (int i = 0; i < 6; ++i) {
        float a0 = P[i][0] + dt * P[i][1] + hd * P[i][2];
        float a1 = P[i][1] + dt * P[i][2];
        float a3 = P[i][3] + dt * P[i][4] + hd * P[i][5];
        float a4 = P[i][4] + dt * P[i][5];
        P[i][0] = a0; P[i][1] = a1; P[i][3] = a3; P[i][4] = a4;
    }
}

// -------- pre-kernel: batch-uniform Kalman gains for the history phase --------
// ws: [t*12..+5]=K0, [t*12+6..+11]=K1 (t<15), [180..215]=P_final
__global__ void kf_precomp(const float* __restrict__ psx, const float* __restrict__ psy,
                           const float* __restrict__ vsx, const float* __restrict__ vsy,
                           const float* __restrict__ asx, const float* __restrict__ asy,
                           const float* __restrict__ jerk, const float* __restrict__ coefG,
                           const float* __restrict__ GRv, float* __restrict__ ws) {
    if (threadIdx.x != 0 || blockIdx.x != 0) return;
    const float dt = 0.2f, g0 = dt * dt * dt / 6.0f, g1 = 0.02f, g2 = dt;
    float gr0 = GRv[0], gr1 = GRv[1];
    float R00 = gr0 * gr0, R01 = gr0 * gr1, R11 = gr1 * gr1;
    float j0 = jerk[0], j1 = jerk[1];
    float qa[3] = {g0 * tanhf(coefG[0]) * j0, g1 * tanhf(coefG[1]) * j0, g2 * tanhf(coefG[2]) * j0};
    float qb[3] = {g0 * tanhf(coefG[3]) * j1, g1 * tanhf(coefG[4]) * j1, g2 * tanhf(coefG[5]) * j1};

    float P[6][6];
    for (int i = 0; i < 6; ++i)
        for (int j = 0; j < 6; ++j) P[i][j] = 0.0f;
    { float v;
      v = psx[0]; P[0][0] = v * v;
      v = vsx[0]; P[1][1] = v * v;
      v = asx[0]; P[2][2] = v * v;
      v = psy[0]; P[3][3] = v * v;
      v = vsy[0]; P[4][4] = v * v;
      v = asy[0]; P[5][5] = v * v; }

    for (int t = 0; t < THIST; ++t) {
        fpft(P);
        for (int i = 0; i < 3; ++i)
            for (int j = 0; j < 3; ++j) {
                P[i][j]         += qa[i] * qa[j];
                P[3 + i][3 + j] += qb[i] * qb[j];
            }
        float S00 = P[0][0] + R00;
        float S01 = P[0][3] + R01;
        float S11 = P[3][3] + R11;
        float idet = 1.0f / (S00 * S11 - S01 * S01);
        float i00 =  S11 * idet, i01 = -S01 * idet, i11 = S00 * idet;
        float K0[6], K1[6];
        for (int i = 0; i < 6; ++i) {
            K0[i] = P[i][0] * i00 + P[i][3] * i01;
            K1[i] = P[i][0] * i01 + P[i][3] * i11;
            ws[t * 12 + i]     = K0[i];
            ws[t * 12 + 6 + i] = K1[i];
        }
        for (int i = 0; i < 6; ++i) {
            P[i][1] -= K0[1] * P[i][0] + K1[1] * P[i][3];
            P[i][2] -= K0[2] * P[i][0] + K1[2] * P[i][3];
            P[i][4] -= K0[4] * P[i][0] + K1[4] * P[i][3];
            P[i][5] -= K0[5] * P[i][0] + K1[5] * P[i][3];
            float t0 = P[i][0] - (K0[0] * P[i][0] + K1[0] * P[i][3]);
            float t3 = P[i][3] - (K0[3] * P[i][0] + K1[3] * P[i][3]);
            P[i][0] = t0; P[i][3] = t3;
        }
    }
    for (int i = 0; i < 6; ++i)
        for (int j = 0; j < 6; ++j) ws[180 + i * 6 + j] = P[i][j];
}

// ------------------------------- main kernel ---------------------------------
// Single-wave block: LDS ops from one wave complete in program order, so NO
// per-step barriers are needed — the compiler's automatic lgkmcnt/vmcnt waits
// preserve dataflow, and loads can hoist across step boundaries.
__global__ __launch_bounds__(BLK, 2)
void kalman_lstm(const float* __restrict__ hist,
                 const float* __restrict__ coefG,
                 const float* __restrict__ cfW, const float* __restrict__ cfb,
                 const float* __restrict__ Wih, const float* __restrict__ Whh,
                 const float* __restrict__ bih, const float* __restrict__ bhh,
                 const float* __restrict__ coW, const float* __restrict__ cob,
                 const float* __restrict__ ws,
                 float* __restrict__ out, int B, int len_pred)
{
    __shared__ float    biasL[128];       // bih+bhh
    __shared__ float    cfwL8[NF * 8];    // [feat][0..5]=cfW row, [6]=cfb, [7]=pad
    __shared__ float    coT[NF * 4];      // [feat][gate]
    __shared__ unsigned hx[32 * HXS];     // h exchange: rows 0..15 hi-plane, 16..31 lo

    const int lane = threadIdx.x;
    const int e = lane & 15;              // element slot (MFMA n-index / D col)
    const int s = lane >> 4;              // quad (k-slice / D row group)
    const int b = blockIdx.x * EPB + e;

    // ---- LDS tables ----
    biasL[lane]      = bih[lane]      + bhh[lane];
    biasL[lane + 64] = bih[lane + 64] + bhh[lane + 64];
    for (int i = lane; i < NF * 8; i += BLK) {
        int f = i >> 3, c = i & 7;
        cfwL8[i] = (c < 6) ? cfW[f * 6 + c] : (c == 6 ? cfb[f] : 0.0f);
    }
    for (int i = lane; i < NF * 4; i += BLK) coT[i] = coW[(i & 3) * NF + (i >> 2)];

    const float dt = 0.2f, hd = 0.02f;
    const float g0 = dt * dt * dt / 6.0f, g1 = 0.02f, g2 = dt;
    float ga0 = g0 * tanhf(coefG[0]);
    float ga1 = g1 * tanhf(coefG[1]);
    float ga2 = g2 * tanhf(coefG[2]);
    float gb3 = g0 * tanhf(coefG[3]);
    float gb4 = g1 * tanhf(coefG[4]);
    float gb5 = g2 * tanhf(coefG[5]);

    // ---- LSTM weights once into register fragments (hi/lo bf16 split) ----
    // A-operand: lane holds W[nt*16 + e][s*8 + j]
    s16x8 wih_h[8], wih_l[8], whh_h[8], whh_l[8];
    #pragma unroll
    for (int nt = 0; nt < 8; ++nt) {
        int base = (nt * 16 + e) * NF + s * 8;
        frag_u ih_h, ih_l, hh_h, hh_l;
        #pragma unroll
        for (int q = 0; q < 4; ++q) {
            bsplit2(Wih[base + 2 * q], Wih[base + 2 * q + 1], ih_h.u[q], ih_l.u[q]);
            bsplit2(Whh[base + 2 * q], Whh[base + 2 * q + 1], hh_h.u[q], hh_l.u[q]);
        }
        wih_h[nt] = ih_h.v; wih_l[nt] = ih_l.v;
        whh_h[nt] = hh_h.v; whh_l[nt] = hh_l.v;
    }

    // ---- Kalman state X (replicated across the 4 s-lanes of each element) ----
    const float2* hist2 = (const float2*)hist;
    float2 z0 = hist2[b];
    float2 z1 = hist2[B + b];
    float X0 = z0.x, X1 = (z1.x - z0.x) / dt, X2 = 0.0f;
    float X3 = (z1.y - z0.y) / dt, X4 = 0.0f, X5 = 0.0f;  // ref overwrites slot 3

    float creg[8], hn[8];
    #pragma unroll
    for (int j = 0; j < 8; ++j) { creg[j] = 0.0f; hn[j] = 0.0f; }
    s16x8 ah_h = (s16x8)0, ah_l = (s16x8)0;

    __syncthreads();   // one-time: tables visible (single wave, cost ~0)

    auto lstm_step = [&]() {
        // feat pairs (8s+2q, 8s+2q+1) from X; b128 row loads, bias in slot 6
        frag_u af_h, af_l;
        #pragma unroll
        for (int q = 0; q < 4; ++q) {
            int f0 = 8 * s + 2 * q;
            f32x4 wa = *(const f32x4*)&cfwL8[f0 * 8];
            f32x4 wb = *(const f32x4*)&cfwL8[f0 * 8 + 4];
            f32x4 wc = *(const f32x4*)&cfwL8[f0 * 8 + 8];
            f32x4 wd = *(const f32x4*)&cfwL8[f0 * 8 + 12];
            float a0 = wb[2] + wa[0] * X0 + wa[1] * X1 + wa[2] * X2
                             + wa[3] * X3 + wb[0] * X4 + wb[1] * X5;
            float a1 = wd[2] + wc[0] * X0 + wc[1] * X1 + wc[2] * X2
                             + wc[3] * X3 + wd[0] * X4 + wd[1] * X5;
            bsplit2(tanhfe(a0), tanhfe(a1), af_h.u[q], af_l.u[q]);
        }

        // gates = Wih@feat + Whh@h + bias via MFMA (hi/lo compensated)
        f32x4 acc[8];
        #pragma unroll
        for (int nt = 0; nt < 8; ++nt)
            acc[nt] = *(const f32x4*)&biasL[nt * 16 + 4 * s];
        #pragma unroll
        for (int nt = 0; nt < 8; ++nt) {
            acc[nt] = __builtin_amdgcn_mfma_f32_16x16x32_bf16(wih_h[nt], af_h.v, acc[nt], 0, 0, 0);
            acc[nt] = __builtin_amdgcn_mfma_f32_16x16x32_bf16(wih_h[nt], af_l.v, acc[nt], 0, 0, 0);
            acc[nt] = __builtin_amdgcn_mfma_f32_16x16x32_bf16(wih_l[nt], af_h.v, acc[nt], 0, 0, 0);
            acc[nt] = __builtin_amdgcn_mfma_f32_16x16x32_bf16(whh_h[nt], ah_h, acc[nt], 0, 0, 0);
            acc[nt] = __builtin_amdgcn_mfma_f32_16x16x32_bf16(whh_h[nt], ah_l, acc[nt], 0, 0, 0);
            acc[nt] = __builtin_amdgcn_mfma_f32_16x16x32_bf16(whh_l[nt], ah_h, acc[nt], 0, 0, 0);
        }

        // combine: tiles {0,1}=i {2,3}=f {4,5}=g {6,7}=o; parity = feature block
        #pragma unroll
        for (int blk = 0; blk < 2; ++blk) {
            float hv[4];
            #pragma unroll
            for (int r = 0; r < 4; ++r) {
                float gi = acc[0 + blk][r];
                float gf = acc[2 + blk][r];
                float gg = acc[4 + blk][r];
                float go = acc[6 + blk][r];
                float cn = sigm(gf) * creg[4 * blk + r] + sigm(gi) * tanhfe(gg);
                creg[4 * blk + r] = cn;
                hv[r] = sigm(go) * tanhfe(cn);
                hn[4 * blk + r] = hv[r];
            }
            // feature-pair rows: (16blk+4s+2rp)/2 = 8blk+2s+rp
            #pragma unroll
            for (int rp = 0; rp < 2; ++rp) {
                unsigned h2, l2;
                bsplit2(hv[2 * rp], hv[2 * rp + 1], h2, l2);
                int row = 8 * blk + 2 * s + rp;
                hx[row * HXS + e]        = h2;   // hi plane
                hx[(16 + row) * HXS + e] = l2;   // lo plane
            }
        }

        // refresh h fragments: consumer (e,s) needs feature pairs 4s..4s+3.
        // Same-wave LDS ordering guarantees these reads see this step's writes.
        frag_u ahh, ahl;
        #pragma unroll
        for (int q = 0; q < 4; ++q) {
            ahh.u[q] = hx[(4 * s + q) * HXS + e];
            ahl.u[q] = hx[(16 + 4 * s + q) * HXS + e];
        }
        ah_h = ahh.v; ah_l = ahl.v;
    };

    // ------------- history phase: X-only update, uniform K via s_load -------------
    #pragma unroll 1
    for (int t = 0; t < THIST; ++t) {
        // issue loads BEFORE the step so their latency hides under compute
        float2 z = hist2[(size_t)(t + 1) * B + b];
        const float* kp = ws + t * 12;            // wave-uniform -> s_load
        float k0 = kp[0],  k1 = kp[1],  k2 = kp[2],  k3 = kp[3];
        float k4 = kp[4],  k5 = kp[5],  k6 = kp[6],  k7 = kp[7];
        float k8 = kp[8],  k9 = kp[9],  k10 = kp[10], k11 = kp[11];

        lstm_step();

        X0 = X0 + dt * X1 + hd * X2;  X1 = X1 + dt * X2;
        X3 = X3 + dt * X4 + hd * X5;  X4 = X4 + dt * X5;
        float y0 = z.x - X0, y1 = z.y - X3;
        X0 += k0 * y0 + k6  * y1;
        X1 += k1 * y0 + k7  * y1;
        X2 += k2 * y0 + k8  * y1;
        X3 += k3 * y0 + k9  * y1;
        X4 += k4 * y0 + k10 * y1;
        X5 += k5 * y0 + k11 * y1;
    }

    // P becomes data-dependent only now; init from uniform post-history P
    float P[6][6];
    #pragma unroll
    for (int i = 0; i < 6; ++i) {
        #pragma unroll
        for (int j = 0; j < 6; ++j) P[i][j] = ws[180 + i * 6 + j];
    }

    // ---------------- prediction phase ----------------
    #pragma unroll 1
    for (int tp = 0; tp < len_pred; ++tp) {
        lstm_step();
        float c0 = 0.0f, c1 = 0.0f, c2 = 0.0f, c3 = 0.0f;
        #pragma unroll
        for (int blk = 0; blk < 2; ++blk)
            #pragma unroll
            for (int r = 0; r < 4; ++r) {
                int f = 16 * blk + 4 * s + r;
                f32x4 w = *(const f32x4*)&coT[f * 4];
                float hk = hn[4 * blk + r];
                c0 += w[0] * hk;
                c1 += w[1] * hk;
                c2 += w[2] * hk;
                c3 += w[3] * hk;
            }
        c0 += __shfl_xor(c0, 16, 64); c0 += __shfl_xor(c0, 32, 64);
        c1 += __shfl_xor(c1, 16, 64); c1 += __shfl_xor(c1, 32, 64);
        c2 += __shfl_xor(c2, 16, 64); c2 += __shfl_xor(c2, 32, 64);
        c3 += __shfl_xor(c3, 16, 64); c3 += __shfl_xor(c3, 32, 64);
        float cmd0 = c0 + cob[0], cmd1 = c1 + cob[1];
        float cmd2 = c2 + cob[2], cmd3 = c3 + cob[3];

        X0 = X0 + dt * X1 + hd * X2 + g0 * cmd0;
        X1 = X1 + dt * X2 + g1 * cmd0;
        X2 = X2 + g2 * cmd0;
        X3 = X3 + dt * X4 + hd * X5 + g0 * cmd1;
        X4 = X4 + dt * X5 + g1 * cmd1;
        X5 = X5 + g2 * cmd1;
        float Gs[6] = {ga0 * cmd2, ga1 * cmd2, ga2 * cmd2,
                       gb3 * cmd3, gb4 * cmd3, gb5 * cmd3};
        fpft(P);
        #pragma unroll
        for (int i = 0; i < 6; ++i)
            #pragma unroll
            for (int j = 0; j < 6; ++j)
                P[i][j] += Gs[i] * Gs[j];

        float sx = sqrtf(P[0][0]), sy = sqrtf(P[3][3]);
        float rho = (P[0][3] + P[3][0]) / (2.0f * sx * sy);
        if (s == 0) {
            size_t o = ((size_t)tp * B + b) * 5u;
            out[o + 0] = X0;
            out[o + 1] = X3;
            out[o + 2] = sx;
            out[o + 3] = sy;
            out[o + 4] = rho;
        }
    }
}

extern "C" void kernel_launch(void* const* d_in, const int* in_sizes, int n_in,
                              void* d_out, int out_size, void* d_ws, size_t ws_size,
                              hipStream_t stream) {
    const int T = 16;
    const int B = in_sizes[0] / (2 * T);      // 32768
    const int len_pred = out_size / (5 * B);  // 25
    float* ws = (float*)d_ws;

    kf_precomp<<<1, 64, 0, stream>>>(
        (const float*)d_in[1], (const float*)d_in[2], (const float*)d_in[3],
        (const float*)d_in[4], (const float*)d_in[5], (const float*)d_in[6],
        (const float*)d_in[7], (const float*)d_in[8], (const float*)d_in[9], ws);

    const int grid = (B + EPB - 1) / EPB;     // one wave per 16 elements
    kalman_lstm<<<grid, BLK, 0, stream>>>(
        (const float*)d_in[0],  (const float*)d_in[8],
        (const float*)d_in[10], (const float*)d_in[11],
        (const float*)d_in[12], (const float*)d_in[13], (const float*)d_in[14],
        (const float*)d_in[15], (const float*)d_in[16], (const float*)d_in[17],
        ws, (float*)d_out, B, len_pred);
}

// Round 9
// 245.121 us; speedup vs baseline: 1.9993x; 1.9993x over previous
//
#include <hip/hip_runtime.h>
#include <hip/hip_bf16.h>
#include <math.h>

#define BLK 64
#define EPB 16            // elements per block (one wave)
#define NF 32
#define THIST 15
#define HXS 18            // hx row stride in u32: reads 2-way max (free)

typedef __attribute__((ext_vector_type(8))) short s16x8;  // 8 bf16 = 4 VGPRs
typedef __attribute__((ext_vector_type(4))) float f32x4;

union frag_u { s16x8 v; unsigned u[4]; };

// raw v_rcp_f32 (~1 ulp) — HIP's __fdividef is NOT fast without -ffast-math;
// it lowers to the precise ~10-inst IEEE div sequence. 48 divs/lane/step made
// that the largest single VALU consumer in R7.
__device__ __forceinline__ float frcp(float x) {
    return __builtin_amdgcn_rcpf(x);
}
__device__ __forceinline__ float sigm(float x) {
    return frcp(1.0f + __expf(-x));
}
// tanh = 1 - 2/(e^{2x}+1); exact saturation, no abs/copysign
__device__ __forceinline__ float tanhfe(float x) {
    float e = __expf(2.0f * x);
    return fmaf(-2.0f, frcp(e + 1.0f), 1.0f);
}
__device__ __forceinline__ float bf16tof(unsigned short h) {
    return __uint_as_float(((unsigned)h) << 16);
}
__device__ __forceinline__ unsigned packbf2(float x0, float x1) {
    __hip_bfloat162 b = __float22bfloat162_rn(float2{x0, x1});
    union { __hip_bfloat162 b; unsigned u; } c; c.b = b; return c.u;
}
// split a PAIR of fp32 into packed-hi / packed-lo bf16 dwords (RNE, ~17-bit eff.)
__device__ __forceinline__ void bsplit2(float x0, float x1, unsigned& h2, unsigned& l2) {
    h2 = packbf2(x0, x1);
    float r0 = x0 - bf16tof((unsigned short)(h2 & 0xffffu));
    float r1 = x1 - bf16tof((unsigned short)(h2 >> 16));
    l2 = packbf2(r0, r1);
}

// P = F P F^T for the constant-accel F (dt=0.2), in place
__device__ __forceinline__ void fpft(float (&P)[6][6]) {
    const float dt = 0.2f, hd = 0.02f;
    #pragma unroll
    for (int j = 0; j < 6; ++j) {
        float a0 = P[0][j] + dt * P[1][j] + hd * P[2][j];
        float a1 = P[1][j] + dt * P[2][j];
        float a3 = P[3][j] + dt * P[4][j] + hd * P[5][j];
        float a4 = P[4][j] + dt * P[5][j];
        P[0][j] = a0; P[1][j] = a1; P[3][j] = a3; P[4][j] = a4;
    }
    #pragma unroll
    for (int i = 0; i < 6; ++i) {
        float a0 = P[i][0] + dt * P[i][1] + hd * P[i][2];
        float a1 = P[i][1] + dt * P[i][2];
        float a3 = P[i][3] + dt * P[i][4] + hd * P[i][5];
        float a4 = P[i][4] + dt * P[i][5];
        P[i][0] = a0; P[i][1] = a1; P[i][3] = a3; P[i][4] = a4;
    }
}

// -------- pre-kernel: batch-uniform Kalman gains for the history phase --------
// ws: [t*12..+5]=K0, [t*12+6..+11]=K1 (t<15), [180..215]=P_final
__global__ void kf_precomp(const float* __restrict__ psx, const float* __restrict__ psy,
                           const float* __restrict__ vsx, const float* __restrict__ vsy,
                           const float* __restrict__ asx, const float* __restrict__ asy,
                           const float* __restrict__ jerk, const float* __restrict__ coefG,
                           const float* __restrict__ GRv, float* __restrict__ ws) {
    if (threadIdx.x != 0 || blockIdx.x != 0) return;
    const float dt = 0.2f, g0 = dt * dt * dt / 6.0f, g1 = 0.02f, g2 = dt;
    float gr0 = GRv[0], gr1 = GRv[1];
    float R00 = gr0 * gr0, R01 = gr0 * gr1, R11 = gr1 * gr1;
    float j0 = jerk[0], j1 = jerk[1];
    float qa[3] = {g0 * tanhf(coefG[0]) * j0, g1 * tanhf(coefG[1]) * j0, g2 * tanhf(coefG[2]) * j0};
    float qb[3] = {g0 * tanhf(coefG[3]) * j1, g1 * tanhf(coefG[4]) * j1, g2 * tanhf(coefG[5]) * j1};

    float P[6][6];
    for (int i = 0; i < 6; ++i)
        for (int j = 0; j < 6; ++j) P[i][j] = 0.0f;
    { float v;
      v = psx[0]; P[0][0] = v * v;
      v = vsx[0]; P[1][1] = v * v;
      v = asx[0]; P[2][2] = v * v;
      v = psy[0]; P[3][3] = v * v;
      v = vsy[0]; P[4][4] = v * v;
      v = asy[0]; P[5][5] = v * v; }

    for (int t = 0; t < THIST; ++t) {
        fpft(P);
        for (int i = 0; i < 3; ++i)
            for (int j = 0; j < 3; ++j) {
                P[i][j]         += qa[i] * qa[j];
                P[3 + i][3 + j] += qb[i] * qb[j];
            }
        float S00 = P[0][0] + R00;
        float S01 = P[0][3] + R01;
        float S11 = P[3][3] + R11;
        float idet = 1.0f / (S00 * S11 - S01 * S01);
        float i00 =  S11 * idet, i01 = -S01 * idet, i11 = S00 * idet;
        float K0[6], K1[6];
        for (int i = 0; i < 6; ++i) {
            K0[i] = P[i][0] * i00 + P[i][3] * i01;
            K1[i] = P[i][0] * i01 + P[i][3] * i11;
            ws[t * 12 + i]     = K0[i];
            ws[t * 12 + 6 + i] = K1[i];
        }
        for (int i = 0; i < 6; ++i) {
            P[i][1] -= K0[1] * P[i][0] + K1[1] * P[i][3];
            P[i][2] -= K0[2] * P[i][0] + K1[2] * P[i][3];
            P[i][4] -= K0[4] * P[i][0] + K1[4] * P[i][3];
            P[i][5] -= K0[5] * P[i][0] + K1[5] * P[i][3];
            float t0 = P[i][0] - (K0[0] * P[i][0] + K1[0] * P[i][3]);
            float t3 = P[i][3] - (K0[3] * P[i][0] + K1[3] * P[i][3]);
            P[i][0] = t0; P[i][3] = t3;
        }
    }
    for (int i = 0; i < 6; ++i)
        for (int j = 0; j < 6; ++j) ws[180 + i * 6 + j] = P[i][j];
}

// ------------------------------- main kernel ---------------------------------
// NOTE: both per-step __syncthreads() are LOAD-BEARING even though the block is
// a single wave — they act as scheduling fences that keep live ranges under the
// 128-arch-VGPR budget. Removing them (R6, R8) caused ~750 MB of scratch spill.
__global__ __launch_bounds__(BLK, 2)
void kalman_lstm(const float* __restrict__ hist,
                 const float* __restrict__ coefG,
                 const float* __restrict__ cfW, const float* __restrict__ cfb,
                 const float* __restrict__ Wih, const float* __restrict__ Whh,
                 const float* __restrict__ bih, const float* __restrict__ bhh,
                 const float* __restrict__ coW, const float* __restrict__ cob,
                 const float* __restrict__ ws,
                 float* __restrict__ out, int B, int len_pred)
{
    __shared__ float    biasL[128];       // bih+bhh
    __shared__ float    cfwL8[NF * 8];    // [feat][0..5]=cfW row, [6]=cfb, [7]=pad
    __shared__ float    coT[NF * 4];      // [feat][gate]
    __shared__ unsigned hx[32 * HXS];     // h exchange: rows 0..15 hi-plane, 16..31 lo

    const int lane = threadIdx.x;
    const int e = lane & 15;              // element slot (MFMA n-index / D col)
    const int s = lane >> 4;              // quad (k-slice / D row group)
    const int b = blockIdx.x * EPB + e;

    // ---- LDS tables ----
    biasL[lane]      = bih[lane]      + bhh[lane];
    biasL[lane + 64] = bih[lane + 64] + bhh[lane + 64];
    for (int i = lane; i < NF * 8; i += BLK) {
        int f = i >> 3, c = i & 7;
        cfwL8[i] = (c < 6) ? cfW[f * 6 + c] : (c == 6 ? cfb[f] : 0.0f);
    }
    for (int i = lane; i < NF * 4; i += BLK) coT[i] = coW[(i & 3) * NF + (i >> 2)];

    const float dt = 0.2f, hd = 0.02f;
    const float g0 = dt * dt * dt / 6.0f, g1 = 0.02f, g2 = dt;
    float ga0 = g0 * tanhf(coefG[0]);
    float ga1 = g1 * tanhf(coefG[1]);
    float ga2 = g2 * tanhf(coefG[2]);
    float gb3 = g0 * tanhf(coefG[3]);
    float gb4 = g1 * tanhf(coefG[4]);
    float gb5 = g2 * tanhf(coefG[5]);

    // ---- LSTM weights once into register fragments (hi/lo bf16 split) ----
    // A-operand: lane holds W[nt*16 + e][s*8 + j]
    s16x8 wih_h[8], wih_l[8], whh_h[8], whh_l[8];
    #pragma unroll
    for (int nt = 0; nt < 8; ++nt) {
        int base = (nt * 16 + e) * NF + s * 8;
        frag_u ih_h, ih_l, hh_h, hh_l;
        #pragma unroll
        for (int q = 0; q < 4; ++q) {
            bsplit2(Wih[base + 2 * q], Wih[base + 2 * q + 1], ih_h.u[q], ih_l.u[q]);
            bsplit2(Whh[base + 2 * q], Whh[base + 2 * q + 1], hh_h.u[q], hh_l.u[q]);
        }
        wih_h[nt] = ih_h.v; wih_l[nt] = ih_l.v;
        whh_h[nt] = hh_h.v; whh_l[nt] = hh_l.v;
    }

    // ---- Kalman state X (replicated across the 4 s-lanes of each element) ----
    const float2* hist2 = (const float2*)hist;
    float2 z0 = hist2[b];
    float2 z1 = hist2[B + b];
    float X0 = z0.x, X1 = (z1.x - z0.x) / dt, X2 = 0.0f;
    float X3 = (z1.y - z0.y) / dt, X4 = 0.0f, X5 = 0.0f;  // ref overwrites slot 3

    float creg[8], hn[8];
    #pragma unroll
    for (int j = 0; j < 8; ++j) { creg[j] = 0.0f; hn[j] = 0.0f; }
    s16x8 ah_h = (s16x8)0, ah_l = (s16x8)0;

    __syncthreads();   // tables visible

    auto lstm_step = [&]() {
        // feat pairs (8s+2q, 8s+2q+1) from X; b128 row loads, bias in slot 6
        frag_u af_h, af_l;
        #pragma unroll
        for (int q = 0; q < 4; ++q) {
            int f0 = 8 * s + 2 * q;
            f32x4 wa = *(const f32x4*)&cfwL8[f0 * 8];
            f32x4 wb = *(const f32x4*)&cfwL8[f0 * 8 + 4];
            f32x4 wc = *(const f32x4*)&cfwL8[f0 * 8 + 8];
            f32x4 wd = *(const f32x4*)&cfwL8[f0 * 8 + 12];
            float a0 = wb[2] + wa[0] * X0 + wa[1] * X1 + wa[2] * X2
                             + wa[3] * X3 + wb[0] * X4 + wb[1] * X5;
            float a1 = wd[2] + wc[0] * X0 + wc[1] * X1 + wc[2] * X2
                             + wc[3] * X3 + wd[0] * X4 + wd[1] * X5;
            bsplit2(tanhfe(a0), tanhfe(a1), af_h.u[q], af_l.u[q]);
        }

        __syncthreads();   // WAR fence (scheduling fence — see note above)

        // gates = Wih@feat + Whh@h + bias via MFMA (hi/lo compensated)
        f32x4 acc[8];
        #pragma unroll
        for (int nt = 0; nt < 8; ++nt)
            acc[nt] = *(const f32x4*)&biasL[nt * 16 + 4 * s];
        #pragma unroll
        for (int nt = 0; nt < 8; ++nt) {
            acc[nt] = __builtin_amdgcn_mfma_f32_16x16x32_bf16(wih_h[nt], af_h.v, acc[nt], 0, 0, 0);
            acc[nt] = __builtin_amdgcn_mfma_f32_16x16x32_bf16(wih_h[nt], af_l.v, acc[nt], 0, 0, 0);
            acc[nt] = __builtin_amdgcn_mfma_f32_16x16x32_bf16(wih_l[nt], af_h.v, acc[nt], 0, 0, 0);
            acc[nt] = __builtin_amdgcn_mfma_f32_16x16x32_bf16(whh_h[nt], ah_h, acc[nt], 0, 0, 0);
            acc[nt] = __builtin_amdgcn_mfma_f32_16x16x32_bf16(whh_h[nt], ah_l, acc[nt], 0, 0, 0);
            acc[nt] = __builtin_amdgcn_mfma_f32_16x16x32_bf16(whh_l[nt], ah_h, acc[nt], 0, 0, 0);
        }

        // combine: tiles {0,1}=i {2,3}=f {4,5}=g {6,7}=o; parity = feature block
        #pragma unroll
        for (int blk = 0; blk < 2; ++blk) {
            float hv[4];
            #pragma unroll
            for (int r = 0; r < 4; ++r) {
                float gi = acc[0 + blk][r];
                float gf = acc[2 + blk][r];
                float gg = acc[4 + blk][r];
                float go = acc[6 + blk][r];
                float cn = sigm(gf) * creg[4 * blk + r] + sigm(gi) * tanhfe(gg);
                creg[4 * blk + r] = cn;
                hv[r] = sigm(go) * tanhfe(cn);
                hn[4 * blk + r] = hv[r];
            }
            // feature-pair rows: (16blk+4s+2rp)/2 = 8blk+2s+rp
            #pragma unroll
            for (int rp = 0; rp < 2; ++rp) {
                unsigned h2, l2;
                bsplit2(hv[2 * rp], hv[2 * rp + 1], h2, l2);
                int row = 8 * blk + 2 * s + rp;
                hx[row * HXS + e]        = h2;   // hi plane
                hx[(16 + row) * HXS + e] = l2;   // lo plane
            }
        }

        __syncthreads();   // RAW fence (scheduling fence — see note above)

        // refresh h fragments: consumer (e,s) needs feature pairs 4s..4s+3
        frag_u ahh, ahl;
        #pragma unroll
        for (int q = 0; q < 4; ++q) {
            ahh.u[q] = hx[(4 * s + q) * HXS + e];
            ahl.u[q] = hx[(16 + 4 * s + q) * HXS + e];
        }
        ah_h = ahh.v; ah_l = ahl.v;
    };

    // ------------- history phase: X-only update, uniform K via s_load -------------
    #pragma unroll 1
    for (int t = 0; t < THIST; ++t) {
        lstm_step();
        float2 z = hist2[(size_t)(t + 1) * B + b];
        const float* kp = ws + t * 12;            // wave-uniform -> s_load
        X0 = X0 + dt * X1 + hd * X2;  X1 = X1 + dt * X2;
        X3 = X3 + dt * X4 + hd * X5;  X4 = X4 + dt * X5;
        float y0 = z.x - X0, y1 = z.y - X3;
        X0 += kp[0] * y0 + kp[6]  * y1;
        X1 += kp[1] * y0 + kp[7]  * y1;
        X2 += kp[2] * y0 + kp[8]  * y1;
        X3 += kp[3] * y0 + kp[9]  * y1;
        X4 += kp[4] * y0 + kp[10] * y1;
        X5 += kp[5] * y0 + kp[11] * y1;
    }

    // P becomes data-dependent only now; init from uniform post-history P
    float P[6][6];
    #pragma unroll
    for (int i = 0; i < 6; ++i) {
        #pragma unroll
        for (int j = 0; j < 6; ++j) P[i][j] = ws[180 + i * 6 + j];
    }

    // ---------------- prediction phase ----------------
    #pragma unroll 1
    for (int tp = 0; tp < len_pred; ++tp) {
        lstm_step();
        float c0 = 0.0f, c1 = 0.0f, c2 = 0.0f, c3 = 0.0f;
        #pragma unroll
        for (int blk = 0; blk < 2; ++blk)
            #pragma unroll
            for (int r = 0; r < 4; ++r) {
                int f = 16 * blk + 4 * s + r;
                f32x4 w = *(const f32x4*)&coT[f * 4];
                float hk = hn[4 * blk + r];
                c0 += w[0] * hk;
                c1 += w[1] * hk;
                c2 += w[2] * hk;
                c3 += w[3] * hk;
            }
        c0 += __shfl_xor(c0, 16, 64); c0 += __shfl_xor(c0, 32, 64);
        c1 += __shfl_xor(c1, 16, 64); c1 += __shfl_xor(c1, 32, 64);
        c2 += __shfl_xor(c2, 16, 64); c2 += __shfl_xor(c2, 32, 64);
        c3 += __shfl_xor(c3, 16, 64); c3 += __shfl_xor(c3, 32, 64);
        float cmd0 = c0 + cob[0], cmd1 = c1 + cob[1];
        float cmd2 = c2 + cob[2], cmd3 = c3 + cob[3];

        X0 = X0 + dt * X1 + hd * X2 + g0 * cmd0;
        X1 = X1 + dt * X2 + g1 * cmd0;
        X2 = X2 + g2 * cmd0;
        X3 = X3 + dt * X4 + hd * X5 + g0 * cmd1;
        X4 = X4 + dt * X5 + g1 * cmd1;
        X5 = X5 + g2 * cmd1;
        float Gs[6] = {ga0 * cmd2, ga1 * cmd2, ga2 * cmd2,
                       gb3 * cmd3, gb4 * cmd3, gb5 * cmd3};
        fpft(P);
        #pragma unroll
        for (int i = 0; i < 6; ++i)
            #pragma unroll
            for (int j = 0; j < 6; ++j)
                P[i][j] += Gs[i] * Gs[j];

        // epilogue stays precise (feeds outputs directly; ~1% of cost)
        float sx = sqrtf(P[0][0]), sy = sqrtf(P[3][3]);
        float rho = (P[0][3] + P[3][0]) / (2.0f * sx * sy);
        if (s == 0) {
            size_t o = ((size_t)tp * B + b) * 5u;
            out[o + 0] = X0;
            out[o + 1] = X3;
            out[o + 2] = sx;
            out[o + 3] = sy;
            out[o + 4] = rho;
        }
    }
}

extern "C" void kernel_launch(void* const* d_in, const int* in_sizes, int n_in,
                              void* d_out, int out_size, void* d_ws, size_t ws_size,
                              hipStream_t stream) {
    const int T = 16;
    const int B = in_sizes[0] / (2 * T);      // 32768
    const int len_pred = out_size / (5 * B);  // 25
    float* ws = (float*)d_ws;

    kf_precomp<<<1, 64, 0, stream>>>(
        (const float*)d_in[1], (const float*)d_in[2], (const float*)d_in[3],
        (const float*)d_in[4], (const float*)d_in[5], (const float*)d_in[6],
        (const float*)d_in[7], (const float*)d_in[8], (const float*)d_in[9], ws);

    const int grid = (B + EPB - 1) / EPB;     // one wave per 16 elements
    kalman_lstm<<<grid, BLK, 0, stream>>>(
        (const float*)d_in[0],  (const float*)d_in[8],
        (const float*)d_in[10], (const float*)d_in[11],
        (const float*)d_in[12], (const float*)d_in[13], (const float*)d_in[14],
        (const float*)d_in[15], (const float*)d_in[16], (const float*)d_in[17],
        ws, (float*)d_out, B, len_pred);
}

// Round 10
// 243.286 us; speedup vs baseline: 2.0144x; 1.0075x over previous
//
#include <hip/hip_runtime.h>
#include <hip/hip_bf16.h>
#include <math.h>

#define BLK 64
#define EPB 16            // elements per block (one wave)
#define NF 32
#define THIST 15
#define HXS 20            // hx row stride in u32: 2s*20 = 8s mod 32 -> s-windows
                          // tile banks at {0,8,16,24} -> exactly 2-way (free)

typedef __attribute__((ext_vector_type(8))) short s16x8;  // 8 bf16 = 4 VGPRs
typedef __attribute__((ext_vector_type(4))) float f32x4;

union frag_u { s16x8 v; unsigned u[4]; };

// raw v_rcp_f32 (~1 ulp) — __fdividef is the precise IEEE seq w/o -ffast-math
__device__ __forceinline__ float frcp(float x) {
    return __builtin_amdgcn_rcpf(x);
}
__device__ __forceinline__ float sigm(float x) {
    return frcp(1.0f + __expf(-x));
}
// tanh = 1 - 2/(e^{2x}+1); exact saturation
__device__ __forceinline__ float tanhfe(float x) {
    float e = __expf(2.0f * x);
    return fmaf(-2.0f, frcp(e + 1.0f), 1.0f);
}
__device__ __forceinline__ float bf16tof(unsigned short h) {
    return __uint_as_float(((unsigned)h) << 16);
}
__device__ __forceinline__ unsigned packbf2(float x0, float x1) {
    __hip_bfloat162 b = __float22bfloat162_rn(float2{x0, x1});
    union { __hip_bfloat162 b; unsigned u; } c; c.b = b; return c.u;
}
// split a PAIR of fp32 into packed-hi / packed-lo bf16 dwords (RNE, ~17-bit eff.)
__device__ __forceinline__ void bsplit2(float x0, float x1, unsigned& h2, unsigned& l2) {
    h2 = packbf2(x0, x1);
    float r0 = x0 - bf16tof((unsigned short)(h2 & 0xffffu));
    float r1 = x1 - bf16tof((unsigned short)(h2 >> 16));
    l2 = packbf2(r0, r1);
}

// P = F P F^T for the constant-accel F (dt=0.2), in place
__device__ __forceinline__ void fpft(float (&P)[6][6]) {
    const float dt = 0.2f, hd = 0.02f;
    #pragma unroll
    for (int j = 0; j < 6; ++j) {
        float a0 = P[0][j] + dt * P[1][j] + hd * P[2][j];
        float a1 = P[1][j] + dt * P[2][j];
        float a3 = P[3][j] + dt * P[4][j] + hd * P[5][j];
        float a4 = P[4][j] + dt * P[5][j];
        P[0][j] = a0; P[1][j] = a1; P[3][j] = a3; P[4][j] = a4;
    }
    #pragma unroll
    for (int i = 0; i < 6; ++i) {
        float a0 = P[i][0] + dt * P[i][1] + hd * P[i][2];
        float a1 = P[i][1] + dt * P[i][2];
        float a3 = P[i][3] + dt * P[i][4] + hd * P[i][5];
        float a4 = P[i][4] + dt * P[i][5];
        P[i][0] = a0; P[i][1] = a1; P[i][3] = a3; P[i][4] = a4;
    }
}

// -------- pre-kernel: batch-uniform Kalman gains for the history phase --------
// ws: [t*12..+5]=K0, [t*12+6..+11]=K1 (t<15), [180..215]=P_final
__global__ void kf_precomp(const float* __restrict__ psx, const float* __restrict__ psy,
                           const float* __restrict__ vsx, const float* __restrict__ vsy,
                           const float* __restrict__ asx, const float* __restrict__ asy,
                           const float* __restrict__ jerk, const float* __restrict__ coefG,
                           const float* __restrict__ GRv, float* __restrict__ ws) {
    if (threadIdx.x != 0 || blockIdx.x != 0) return;
    const float dt = 0.2f, g0 = dt * dt * dt / 6.0f, g1 = 0.02f, g2 = dt;
    float gr0 = GRv[0], gr1 = GRv[1];
    float R00 = gr0 * gr0, R01 = gr0 * gr1, R11 = gr1 * gr1;
    float j0 = jerk[0], j1 = jerk[1];
    float qa[3] = {g0 * tanhf(coefG[0]) * j0, g1 * tanhf(coefG[1]) * j0, g2 * tanhf(coefG[2]) * j0};
    float qb[3] = {g0 * tanhf(coefG[3]) * j1, g1 * tanhf(coefG[4]) * j1, g2 * tanhf(coefG[5]) * j1};

    float P[6][6];
    for (int i = 0; i < 6; ++i)
        for (int j = 0; j < 6; ++j) P[i][j] = 0.0f;
    { float v;
      v = psx[0]; P[0][0] = v * v;
      v = vsx[0]; P[1][1] = v * v;
      v = asx[0]; P[2][2] = v * v;
      v = psy[0]; P[3][3] = v * v;
      v = vsy[0]; P[4][4] = v * v;
      v = asy[0]; P[5][5] = v * v; }

    for (int t = 0; t < THIST; ++t) {
        fpft(P);
        for (int i = 0; i < 3; ++i)
            for (int j = 0; j < 3; ++j) {
                P[i][j]         += qa[i] * qa[j];
                P[3 + i][3 + j] += qb[i] * qb[j];
            }
        float S00 = P[0][0] + R00;
        float S01 = P[0][3] + R01;
        float S11 = P[3][3] + R11;
        float idet = 1.0f / (S00 * S11 - S01 * S01);
        float i00 =  S11 * idet, i01 = -S01 * idet, i11 = S00 * idet;
        float K0[6], K1[6];
        for (int i = 0; i < 6; ++i) {
            K0[i] = P[i][0] * i00 + P[i][3] * i01;
            K1[i] = P[i][0] * i01 + P[i][3] * i11;
            ws[t * 12 + i]     = K0[i];
            ws[t * 12 + 6 + i] = K1[i];
        }
        for (int i = 0; i < 6; ++i) {
            P[i][1] -= K0[1] * P[i][0] + K1[1] * P[i][3];
            P[i][2] -= K0[2] * P[i][0] + K1[2] * P[i][3];
            P[i][4] -= K0[4] * P[i][0] + K1[4] * P[i][3];
            P[i][5] -= K0[5] * P[i][0] + K1[5] * P[i][3];
            float t0 = P[i][0] - (K0[0] * P[i][0] + K1[0] * P[i][3]);
            float t3 = P[i][3] - (K0[3] * P[i][0] + K1[3] * P[i][3]);
            P[i][0] = t0; P[i][3] = t3;
        }
    }
    for (int i = 0; i < 6; ++i)
        for (int j = 0; j < 6; ++j) ws[180 + i * 6 + j] = P[i][j];
}

// ------------------------------- main kernel ---------------------------------
// The post-write __syncthreads() per step is LOAD-BEARING as a scheduling fence
// (keeps live ranges under the 128-arch-VGPR budget; removing both fences in
// R6/R8 caused ~750 MB scratch spill). The pre-MFMA fence was redundant
// (same-wave LDS ordering covers the WAR hazard) and is removed here.
__global__ __launch_bounds__(BLK, 2)
void kalman_lstm(const float* __restrict__ hist,
                 const float* __restrict__ coefG,
                 const float* __restrict__ cfW, const float* __restrict__ cfb,
                 const float* __restrict__ Wih, const float* __restrict__ Whh,
                 const float* __restrict__ bih, const float* __restrict__ bhh,
                 const float* __restrict__ coW, const float* __restrict__ cob,
                 const float* __restrict__ ws,
                 float* __restrict__ out, int B, int len_pred)
{
    __shared__ float    biasL[128];       // bih+bhh
    // cfW pair-interleaved: pair p -> [16p+0..5]=w(2p), [16p+6]=cfb(2p),
    // [16p+8..13]=w(2p+1), [16p+14]=cfb(2p+1). Read address 16p+{0,4,8,12} is
    // independent of lane's s (p=4s+q cancels mod 32) -> 64-lane broadcast,
    // conflict-free b128 reads.
    __shared__ float    cfwP[16 * 16];
    __shared__ float    coT[NF * 4];      // [feat][gate]
    __shared__ unsigned hx[32 * HXS];     // h exchange: rows 0..15 hi, 16..31 lo

    const int lane = threadIdx.x;
    const int e = lane & 15;              // element slot (MFMA n-index / D col)
    const int s = lane >> 4;              // quad (k-slice / D row group)
    const int b = blockIdx.x * EPB + e;

    // ---- LDS tables ----
    biasL[lane]      = bih[lane]      + bhh[lane];
    biasL[lane + 64] = bih[lane + 64] + bhh[lane + 64];
    for (int i = lane; i < 16 * 16; i += BLK) {
        int p = i >> 4, c = i & 15;
        float v = 0.0f;
        if (c < 6)        v = cfW[(2 * p) * 6 + c];
        else if (c == 6)  v = cfb[2 * p];
        else if (c >= 8 && c < 14) v = cfW[(2 * p + 1) * 6 + (c - 8)];
        else if (c == 14) v = cfb[2 * p + 1];
        cfwP[i] = v;
    }
    for (int i = lane; i < NF * 4; i += BLK) coT[i] = coW[(i & 3) * NF + (i >> 2)];

    const float dt = 0.2f, hd = 0.02f;
    const float g0 = dt * dt * dt / 6.0f, g1 = 0.02f, g2 = dt;
    float ga0 = g0 * tanhf(coefG[0]);
    float ga1 = g1 * tanhf(coefG[1]);
    float ga2 = g2 * tanhf(coefG[2]);
    float gb3 = g0 * tanhf(coefG[3]);
    float gb4 = g1 * tanhf(coefG[4]);
    float gb5 = g2 * tanhf(coefG[5]);

    // ---- LSTM weights once into register fragments (hi/lo bf16 split) ----
    // A-operand: lane holds W[nt*16 + e][s*8 + j]
    s16x8 wih_h[8], wih_l[8], whh_h[8], whh_l[8];
    #pragma unroll
    for (int nt = 0; nt < 8; ++nt) {
        int base = (nt * 16 + e) * NF + s * 8;
        frag_u ih_h, ih_l, hh_h, hh_l;
        #pragma unroll
        for (int q = 0; q < 4; ++q) {
            bsplit2(Wih[base + 2 * q], Wih[base + 2 * q + 1], ih_h.u[q], ih_l.u[q]);
            bsplit2(Whh[base + 2 * q], Whh[base + 2 * q + 1], hh_h.u[q], hh_l.u[q]);
        }
        wih_h[nt] = ih_h.v; wih_l[nt] = ih_l.v;
        whh_h[nt] = hh_h.v; whh_l[nt] = hh_l.v;
    }

    // ---- Kalman state X (replicated across the 4 s-lanes of each element) ----
    const float2* hist2 = (const float2*)hist;
    float2 z0 = hist2[b];
    float2 z1 = hist2[B + b];
    float X0 = z0.x, X1 = (z1.x - z0.x) / dt, X2 = 0.0f;
    float X3 = (z1.y - z0.y) / dt, X4 = 0.0f, X5 = 0.0f;  // ref overwrites slot 3

    float creg[8], hn[8];
    #pragma unroll
    for (int j = 0; j < 8; ++j) { creg[j] = 0.0f; hn[j] = 0.0f; }
    s16x8 ah_h = (s16x8)0, ah_l = (s16x8)0;

    __syncthreads();   // tables visible

    auto lstm_step = [&]() {
        // feat pairs (8s+2q, 8s+2q+1) = pair p=4s+q; conflict-free b128 loads
        frag_u af_h, af_l;
        #pragma unroll
        for (int q = 0; q < 4; ++q) {
            int p16 = (4 * s + q) * 16;
            f32x4 wa = *(const f32x4*)&cfwP[p16];
            f32x4 wb = *(const f32x4*)&cfwP[p16 + 4];
            f32x4 wc = *(const f32x4*)&cfwP[p16 + 8];
            f32x4 wd = *(const f32x4*)&cfwP[p16 + 12];
            float a0 = wb[2] + wa[0] * X0 + wa[1] * X1 + wa[2] * X2
                             + wa[3] * X3 + wb[0] * X4 + wb[1] * X5;
            float a1 = wd[2] + wc[0] * X0 + wc[1] * X1 + wc[2] * X2
                             + wc[3] * X3 + wd[0] * X4 + wd[1] * X5;
            bsplit2(tanhfe(a0), tanhfe(a1), af_h.u[q], af_l.u[q]);
        }

        // (no barrier here: same-wave LDS ordering covers the WAR hazard)

        // gates = Wih@feat + Whh@h + bias via MFMA (hi/lo compensated)
        f32x4 acc[8];
        #pragma unroll
        for (int nt = 0; nt < 8; ++nt)
            acc[nt] = *(const f32x4*)&biasL[nt * 16 + 4 * s];
        #pragma unroll
        for (int nt = 0; nt < 8; ++nt) {
            acc[nt] = __builtin_amdgcn_mfma_f32_16x16x32_bf16(wih_h[nt], af_h.v, acc[nt], 0, 0, 0);
            acc[nt] = __builtin_amdgcn_mfma_f32_16x16x32_bf16(wih_h[nt], af_l.v, acc[nt], 0, 0, 0);
            acc[nt] = __builtin_amdgcn_mfma_f32_16x16x32_bf16(wih_l[nt], af_h.v, acc[nt], 0, 0, 0);
            acc[nt] = __builtin_amdgcn_mfma_f32_16x16x32_bf16(whh_h[nt], ah_h, acc[nt], 0, 0, 0);
            acc[nt] = __builtin_amdgcn_mfma_f32_16x16x32_bf16(whh_h[nt], ah_l, acc[nt], 0, 0, 0);
            acc[nt] = __builtin_amdgcn_mfma_f32_16x16x32_bf16(whh_l[nt], ah_h, acc[nt], 0, 0, 0);
        }

        // combine: tiles {0,1}=i {2,3}=f {4,5}=g {6,7}=o; parity = feature block
        #pragma unroll
        for (int blk = 0; blk < 2; ++blk) {
            float hv[4];
            #pragma unroll
            for (int r = 0; r < 4; ++r) {
                float gi = acc[0 + blk][r];
                float gf = acc[2 + blk][r];
                float gg = acc[4 + blk][r];
                float go = acc[6 + blk][r];
                float cn = sigm(gf) * creg[4 * blk + r] + sigm(gi) * tanhfe(gg);
                creg[4 * blk + r] = cn;
                hv[r] = sigm(go) * tanhfe(cn);
                hn[4 * blk + r] = hv[r];
            }
            // feature-pair rows: (16blk+4s+2rp)/2 = 8blk+2s+rp
            #pragma unroll
            for (int rp = 0; rp < 2; ++rp) {
                unsigned h2, l2;
                bsplit2(hv[2 * rp], hv[2 * rp + 1], h2, l2);
                int row = 8 * blk + 2 * s + rp;
                hx[row * HXS + e]        = h2;   // hi plane
                hx[(16 + row) * HXS + e] = l2;   // lo plane
            }
        }

        __syncthreads();   // RAW + scheduling fence (load-bearing, see note)

        // refresh h fragments: consumer (e,s) needs feature pairs 4s..4s+3
        frag_u ahh, ahl;
        #pragma unroll
        for (int q = 0; q < 4; ++q) {
            ahh.u[q] = hx[(4 * s + q) * HXS + e];
            ahl.u[q] = hx[(16 + 4 * s + q) * HXS + e];
        }
        ah_h = ahh.v; ah_l = ahl.v;
    };

    // ------------- history phase: X-only update, uniform K via s_load -------------
    #pragma unroll 1
    for (int t = 0; t < THIST; ++t) {
        lstm_step();
        float2 z = hist2[(size_t)(t + 1) * B + b];
        const float* kp = ws + t * 12;            // wave-uniform -> s_load
        X0 = X0 + dt * X1 + hd * X2;  X1 = X1 + dt * X2;
        X3 = X3 + dt * X4 + hd * X5;  X4 = X4 + dt * X5;
        float y0 = z.x - X0, y1 = z.y - X3;
        X0 += kp[0] * y0 + kp[6]  * y1;
        X1 += kp[1] * y0 + kp[7]  * y1;
        X2 += kp[2] * y0 + kp[8]  * y1;
        X3 += kp[3] * y0 + kp[9]  * y1;
        X4 += kp[4] * y0 + kp[10] * y1;
        X5 += kp[5] * y0 + kp[11] * y1;
    }

    // P becomes data-dependent only now; init from uniform post-history P
    float P[6][6];
    #pragma unroll
    for (int i = 0; i < 6; ++i) {
        #pragma unroll
        for (int j = 0; j < 6; ++j) P[i][j] = ws[180 + i * 6 + j];
    }

    // ---------------- prediction phase ----------------
    #pragma unroll 1
    for (int tp = 0; tp < len_pred; ++tp) {
        lstm_step();
        float c0 = 0.0f, c1 = 0.0f, c2 = 0.0f, c3 = 0.0f;
        #pragma unroll
        for (int blk = 0; blk < 2; ++blk)
            #pragma unroll
            for (int r = 0; r < 4; ++r) {
                int f = 16 * blk + 4 * s + r;
                f32x4 w = *(const f32x4*)&coT[f * 4];
                float hk = hn[4 * blk + r];
                c0 += w[0] * hk;
                c1 += w[1] * hk;
                c2 += w[2] * hk;
                c3 += w[3] * hk;
            }
        c0 += __shfl_xor(c0, 16, 64); c0 += __shfl_xor(c0, 32, 64);
        c1 += __shfl_xor(c1, 16, 64); c1 += __shfl_xor(c1, 32, 64);
        c2 += __shfl_xor(c2, 16, 64); c2 += __shfl_xor(c2, 32, 64);
        c3 += __shfl_xor(c3, 16, 64); c3 += __shfl_xor(c3, 32, 64);
        float cmd0 = c0 + cob[0], cmd1 = c1 + cob[1];
        float cmd2 = c2 + cob[2], cmd3 = c3 + cob[3];

        X0 = X0 + dt * X1 + hd * X2 + g0 * cmd0;
        X1 = X1 + dt * X2 + g1 * cmd0;
        X2 = X2 + g2 * cmd0;
        X3 = X3 + dt * X4 + hd * X5 + g0 * cmd1;
        X4 = X4 + dt * X5 + g1 * cmd1;
        X5 = X5 + g2 * cmd1;
        float Gs[6] = {ga0 * cmd2, ga1 * cmd2, ga2 * cmd2,
                       gb3 * cmd3, gb4 * cmd3, gb5 * cmd3};
        fpft(P);
        #pragma unroll
        for (int i = 0; i < 6; ++i)
            #pragma unroll
            for (int j = 0; j < 6; ++j)
                P[i][j] += Gs[i] * Gs[j];

        // epilogue stays precise (feeds outputs directly; ~1% of cost)
        float sx = sqrtf(P[0][0]), sy = sqrtf(P[3][3]);
        float rho = (P[0][3] + P[3][0]) / (2.0f * sx * sy);
        if (s == 0) {
            size_t o = ((size_t)tp * B + b) * 5u;
            out[o + 0] = X0;
            out[o + 1] = X3;
            out[o + 2] = sx;
            out[o + 3] = sy;
            out[o + 4] = rho;
        }
    }
}

extern "C" void kernel_launch(void* const* d_in, const int* in_sizes, int n_in,
                              void* d_out, int out_size, void* d_ws, size_t ws_size,
                              hipStream_t stream) {
    const int T = 16;
    const int B = in_sizes[0] / (2 * T);      // 32768
    const int len_pred = out_size / (5 * B);  // 25
    float* ws = (float*)d_ws;

    kf_precomp<<<1, 64, 0, stream>>>(
        (const float*)d_in[1], (const float*)d_in[2], (const float*)d_in[3],
        (const float*)d_in[4], (const float*)d_in[5], (const float*)d_in[6],
        (const float*)d_in[7], (const float*)d_in[8], (const float*)d_in[9], ws);

    const int grid = (B + EPB - 1) / EPB;     // one wave per 16 elements
    kalman_lstm<<<grid, BLK, 0, stream>>>(
        (const float*)d_in[0],  (const float*)d_in[8],
        (const float*)d_in[10], (const float*)d_in[11],
        (const float*)d_in[12], (const float*)d_in[13], (const float*)d_in[14],
        (const float*)d_in[15], (const float*)d_in[16], (const float*)d_in[17],
        ws, (float*)d_out, B, len_pred);
}

// Round 11
// 242.942 us; speedup vs baseline: 2.0173x; 1.0014x over previous
//
#include <hip/hip_runtime.h>
#include <hip/hip_bf16.h>
#include <math.h>

#define BLK 64
#define EPB 16            // elements per block (one wave)
#define NF 32
#define THIST 15
#define HXS 20            // hx row stride in u32: 2s*20 = 8s mod 32 -> s-windows
                          // tile banks at {0,8,16,24} -> exactly 2-way (free)

typedef __attribute__((ext_vector_type(8))) short s16x8;  // 8 bf16 = 4 VGPRs
typedef __attribute__((ext_vector_type(4))) float f32x4;

union frag_u { s16x8 v; unsigned u[4]; };

// raw v_rcp_f32 (~1 ulp) — __fdividef is the precise IEEE seq w/o -ffast-math
__device__ __forceinline__ float frcp(float x) {
    return __builtin_amdgcn_rcpf(x);
}
__device__ __forceinline__ float sigm(float x) {
    return frcp(1.0f + __expf(-x));
}
// tanh = 1 - 2/(e^{2x}+1); exact saturation
__device__ __forceinline__ float tanhfe(float x) {
    float e = __expf(2.0f * x);
    return fmaf(-2.0f, frcp(e + 1.0f), 1.0f);
}
__device__ __forceinline__ float bf16tof(unsigned short h) {
    return __uint_as_float(((unsigned)h) << 16);
}
__device__ __forceinline__ unsigned packbf2(float x0, float x1) {
    __hip_bfloat162 b = __float22bfloat162_rn(float2{x0, x1});
    union { __hip_bfloat162 b; unsigned u; } c; c.b = b; return c.u;
}
// split a PAIR of fp32 into packed-hi / packed-lo bf16 dwords (RNE, ~17-bit eff.)
__device__ __forceinline__ void bsplit2(float x0, float x1, unsigned& h2, unsigned& l2) {
    h2 = packbf2(x0, x1);
    float r0 = x0 - bf16tof((unsigned short)(h2 & 0xffffu));
    float r1 = x1 - bf16tof((unsigned short)(h2 >> 16));
    l2 = packbf2(r0, r1);
}

// P = F P F^T for the constant-accel F (dt=0.2), in place
__device__ __forceinline__ void fpft(float (&P)[6][6]) {
    const float dt = 0.2f, hd = 0.02f;
    #pragma unroll
    for (int j = 0; j < 6; ++j) {
        float a0 = P[0][j] + dt * P[1][j] + hd * P[2][j];
        float a1 = P[1][j] + dt * P[2][j];
        float a3 = P[3][j] + dt * P[4][j] + hd * P[5][j];
        float a4 = P[4][j] + dt * P[5][j];
        P[0][j] = a0; P[1][j] = a1; P[3][j] = a3; P[4][j] = a4;
    }
    #pragma unroll
    for (int i = 0; i < 6; ++i) {
        float a0 = P[i][0] + dt * P[i][1] + hd * P[i][2];
        float a1 = P[i][1] + dt * P[i][2];
        float a3 = P[i][3] + dt * P[i][4] + hd * P[i][5];
        float a4 = P[i][4] + dt * P[i][5];
        P[i][0] = a0; P[i][1] = a1; P[i][3] = a3; P[i][4] = a4;
    }
}

// -------- pre-kernel: batch-uniform Kalman gains for the history phase --------
// ws: [t*12..+5]=K0, [t*12+6..+11]=K1 (t<15), [180..215]=P_final
__global__ void kf_precomp(const float* __restrict__ psx, const float* __restrict__ psy,
                           const float* __restrict__ vsx, const float* __restrict__ vsy,
                           const float* __restrict__ asx, const float* __restrict__ asy,
                           const float* __restrict__ jerk, const float* __restrict__ coefG,
                           const float* __restrict__ GRv, float* __restrict__ ws) {
    if (threadIdx.x != 0 || blockIdx.x != 0) return;
    const float dt = 0.2f, g0 = dt * dt * dt / 6.0f, g1 = 0.02f, g2 = dt;
    float gr0 = GRv[0], gr1 = GRv[1];
    float R00 = gr0 * gr0, R01 = gr0 * gr1, R11 = gr1 * gr1;
    float j0 = jerk[0], j1 = jerk[1];
    float qa[3] = {g0 * tanhf(coefG[0]) * j0, g1 * tanhf(coefG[1]) * j0, g2 * tanhf(coefG[2]) * j0};
    float qb[3] = {g0 * tanhf(coefG[3]) * j1, g1 * tanhf(coefG[4]) * j1, g2 * tanhf(coefG[5]) * j1};

    float P[6][6];
    for (int i = 0; i < 6; ++i)
        for (int j = 0; j < 6; ++j) P[i][j] = 0.0f;
    { float v;
      v = psx[0]; P[0][0] = v * v;
      v = vsx[0]; P[1][1] = v * v;
      v = asx[0]; P[2][2] = v * v;
      v = psy[0]; P[3][3] = v * v;
      v = vsy[0]; P[4][4] = v * v;
      v = asy[0]; P[5][5] = v * v; }

    for (int t = 0; t < THIST; ++t) {
        fpft(P);
        for (int i = 0; i < 3; ++i)
            for (int j = 0; j < 3; ++j) {
                P[i][j]         += qa[i] * qa[j];
                P[3 + i][3 + j] += qb[i] * qb[j];
            }
        float S00 = P[0][0] + R00;
        float S01 = P[0][3] + R01;
        float S11 = P[3][3] + R11;
        float idet = 1.0f / (S00 * S11 - S01 * S01);
        float i00 =  S11 * idet, i01 = -S01 * idet, i11 = S00 * idet;
        float K0[6], K1[6];
        for (int i = 0; i < 6; ++i) {
            K0[i] = P[i][0] * i00 + P[i][3] * i01;
            K1[i] = P[i][0] * i01 + P[i][3] * i11;
            ws[t * 12 + i]     = K0[i];
            ws[t * 12 + 6 + i] = K1[i];
        }
        for (int i = 0; i < 6; ++i) {
            P[i][1] -= K0[1] * P[i][0] + K1[1] * P[i][3];
            P[i][2] -= K0[2] * P[i][0] + K1[2] * P[i][3];
            P[i][4] -= K0[4] * P[i][0] + K1[4] * P[i][3];
            P[i][5] -= K0[5] * P[i][0] + K1[5] * P[i][3];
            float t0 = P[i][0] - (K0[0] * P[i][0] + K1[0] * P[i][3]);
            float t3 = P[i][3] - (K0[3] * P[i][0] + K1[3] * P[i][3]);
            P[i][0] = t0; P[i][3] = t3;
        }
    }
    for (int i = 0; i < 6; ++i)
        for (int j = 0; j < 6; ++j) ws[180 + i * 6 + j] = P[i][j];
}

// ------------------------------- main kernel ---------------------------------
// Fence history: R6/R8 (no fence) -> scheduler hoists across steps -> ~750 MB
// scratch spill. R5/R7/R10 (s_barrier fence) -> no spill, but the compiler's
// mandatory `s_waitcnt vmcnt(0) lgkmcnt(0)` before s_barrier drains the out-
// stores / z-prefetch EVERY step (serial bubble). This version replaces the
// runtime barrier with __builtin_amdgcn_sched_barrier(0): a compile-time fence
// that pins instruction ordering (containing live ranges) with ZERO runtime
// cost and no vmcnt drain. Correctness without s_barrier is safe: single-wave
// block, same-wave LDS ops execute in order (proven by R8: absmax 2.0).
__global__ __launch_bounds__(BLK, 2)
void kalman_lstm(const float* __restrict__ hist,
                 const float* __restrict__ coefG,
                 const float* __restrict__ cfW, const float* __restrict__ cfb,
                 const float* __restrict__ Wih, const float* __restrict__ Whh,
                 const float* __restrict__ bih, const float* __restrict__ bhh,
                 const float* __restrict__ coW, const float* __restrict__ cob,
                 const float* __restrict__ ws,
                 float* __restrict__ out, int B, int len_pred)
{
    __shared__ float    biasL[128];       // bih+bhh
    // cfW pair-interleaved: pair p -> [16p+0..5]=w(2p), [16p+6]=cfb(2p),
    // [16p+8..13]=w(2p+1), [16p+14]=cfb(2p+1). Address 16p+{0,4,8,12} is
    // independent of lane's s -> 64-lane broadcast, conflict-free b128 reads.
    __shared__ float    cfwP[16 * 16];
    __shared__ float    coT[NF * 4];      // [feat][gate]
    __shared__ unsigned hx[32 * HXS];     // h exchange: rows 0..15 hi, 16..31 lo

    const int lane = threadIdx.x;
    const int e = lane & 15;              // element slot (MFMA n-index / D col)
    const int s = lane >> 4;              // quad (k-slice / D row group)
    const int b = blockIdx.x * EPB + e;

    // ---- LDS tables ----
    biasL[lane]      = bih[lane]      + bhh[lane];
    biasL[lane + 64] = bih[lane + 64] + bhh[lane + 64];
    for (int i = lane; i < 16 * 16; i += BLK) {
        int p = i >> 4, c = i & 15;
        float v = 0.0f;
        if (c < 6)        v = cfW[(2 * p) * 6 + c];
        else if (c == 6)  v = cfb[2 * p];
        else if (c >= 8 && c < 14) v = cfW[(2 * p + 1) * 6 + (c - 8)];
        else if (c == 14) v = cfb[2 * p + 1];
        cfwP[i] = v;
    }
    for (int i = lane; i < NF * 4; i += BLK) coT[i] = coW[(i & 3) * NF + (i >> 2)];

    const float dt = 0.2f, hd = 0.02f;
    const float g0 = dt * dt * dt / 6.0f, g1 = 0.02f, g2 = dt;
    float ga0 = g0 * tanhf(coefG[0]);
    float ga1 = g1 * tanhf(coefG[1]);
    float ga2 = g2 * tanhf(coefG[2]);
    float gb3 = g0 * tanhf(coefG[3]);
    float gb4 = g1 * tanhf(coefG[4]);
    float gb5 = g2 * tanhf(coefG[5]);

    // ---- LSTM weights once into register fragments (hi/lo bf16 split) ----
    // A-operand: lane holds W[nt*16 + e][s*8 + j]
    s16x8 wih_h[8], wih_l[8], whh_h[8], whh_l[8];
    #pragma unroll
    for (int nt = 0; nt < 8; ++nt) {
        int base = (nt * 16 + e) * NF + s * 8;
        frag_u ih_h, ih_l, hh_h, hh_l;
        #pragma unroll
        for (int q = 0; q < 4; ++q) {
            bsplit2(Wih[base + 2 * q], Wih[base + 2 * q + 1], ih_h.u[q], ih_l.u[q]);
            bsplit2(Whh[base + 2 * q], Whh[base + 2 * q + 1], hh_h.u[q], hh_l.u[q]);
        }
        wih_h[nt] = ih_h.v; wih_l[nt] = ih_l.v;
        whh_h[nt] = hh_h.v; whh_l[nt] = hh_l.v;
    }

    // ---- Kalman state X (replicated across the 4 s-lanes of each element) ----
    const float2* hist2 = (const float2*)hist;
    float2 z0 = hist2[b];
    float2 z1 = hist2[B + b];
    float X0 = z0.x, X1 = (z1.x - z0.x) / dt, X2 = 0.0f;
    float X3 = (z1.y - z0.y) / dt, X4 = 0.0f, X5 = 0.0f;  // ref overwrites slot 3

    float creg[8], hn[8];
    #pragma unroll
    for (int j = 0; j < 8; ++j) { creg[j] = 0.0f; hn[j] = 0.0f; }
    s16x8 ah_h = (s16x8)0, ah_l = (s16x8)0;

    __syncthreads();   // one-time: tables visible

    auto lstm_step = [&]() {
        // feat pairs (8s+2q, 8s+2q+1) = pair p=4s+q; conflict-free b128 loads
        frag_u af_h, af_l;
        #pragma unroll
        for (int q = 0; q < 4; ++q) {
            int p16 = (4 * s + q) * 16;
            f32x4 wa = *(const f32x4*)&cfwP[p16];
            f32x4 wb = *(const f32x4*)&cfwP[p16 + 4];
            f32x4 wc = *(const f32x4*)&cfwP[p16 + 8];
            f32x4 wd = *(const f32x4*)&cfwP[p16 + 12];
            float a0 = wb[2] + wa[0] * X0 + wa[1] * X1 + wa[2] * X2
                             + wa[3] * X3 + wb[0] * X4 + wb[1] * X5;
            float a1 = wd[2] + wc[0] * X0 + wc[1] * X1 + wc[2] * X2
                             + wc[3] * X3 + wd[0] * X4 + wd[1] * X5;
            bsplit2(tanhfe(a0), tanhfe(a1), af_h.u[q], af_l.u[q]);
        }

        // gates = Wih@feat + Whh@h + bias via MFMA (hi/lo compensated)
        f32x4 acc[8];
        #pragma unroll
        for (int nt = 0; nt < 8; ++nt)
            acc[nt] = *(const f32x4*)&biasL[nt * 16 + 4 * s];
        #pragma unroll
        for (int nt = 0; nt < 8; ++nt) {
            acc[nt] = __builtin_amdgcn_mfma_f32_16x16x32_bf16(wih_h[nt], af_h.v, acc[nt], 0, 0, 0);
            acc[nt] = __builtin_amdgcn_mfma_f32_16x16x32_bf16(wih_h[nt], af_l.v, acc[nt], 0, 0, 0);
            acc[nt] = __builtin_amdgcn_mfma_f32_16x16x32_bf16(wih_l[nt], af_h.v, acc[nt], 0, 0, 0);
            acc[nt] = __builtin_amdgcn_mfma_f32_16x16x32_bf16(whh_h[nt], ah_h, acc[nt], 0, 0, 0);
            acc[nt] = __builtin_amdgcn_mfma_f32_16x16x32_bf16(whh_h[nt], ah_l, acc[nt], 0, 0, 0);
            acc[nt] = __builtin_amdgcn_mfma_f32_16x16x32_bf16(whh_l[nt], ah_h, acc[nt], 0, 0, 0);
        }

        // combine: tiles {0,1}=i {2,3}=f {4,5}=g {6,7}=o; parity = feature block
        #pragma unroll
        for (int blk = 0; blk < 2; ++blk) {
            float hv[4];
            #pragma unroll
            for (int r = 0; r < 4; ++r) {
                float gi = acc[0 + blk][r];
                float gf = acc[2 + blk][r];
                float gg = acc[4 + blk][r];
                float go = acc[6 + blk][r];
                float cn = sigm(gf) * creg[4 * blk + r] + sigm(gi) * tanhfe(gg);
                creg[4 * blk + r] = cn;
                hv[r] = sigm(go) * tanhfe(cn);
                hn[4 * blk + r] = hv[r];
            }
            // feature-pair rows: (16blk+4s+2rp)/2 = 8blk+2s+rp
            #pragma unroll
            for (int rp = 0; rp < 2; ++rp) {
                unsigned h2, l2;
                bsplit2(hv[2 * rp], hv[2 * rp + 1], h2, l2);
                int row = 8 * blk + 2 * s + rp;
                hx[row * HXS + e]        = h2;   // hi plane
                hx[(16 + row) * HXS + e] = l2;   // lo plane
            }
        }

        // Compile-time fence: pins ordering (live-range containment, prevents
        // the R6/R8 spill) with no runtime s_barrier / vmcnt(0) drain.
        __builtin_amdgcn_sched_barrier(0);

        // refresh h fragments: consumer (e,s) needs feature pairs 4s..4s+3.
        // Same-wave LDS ordering guarantees these reads see this step's writes.
        frag_u ahh, ahl;
        #pragma unroll
        for (int q = 0; q < 4; ++q) {
            ahh.u[q] = hx[(4 * s + q) * HXS + e];
            ahl.u[q] = hx[(16 + 4 * s + q) * HXS + e];
        }
        ah_h = ahh.v; ah_l = ahl.v;
    };

    // ------------- history phase: X-only update, uniform K via s_load -------------
    #pragma unroll 1
    for (int t = 0; t < THIST; ++t) {
        lstm_step();
        float2 z = hist2[(size_t)(t + 1) * B + b];
        const float* kp = ws + t * 12;            // wave-uniform -> s_load
        X0 = X0 + dt * X1 + hd * X2;  X1 = X1 + dt * X2;
        X3 = X3 + dt * X4 + hd * X5;  X4 = X4 + dt * X5;
        float y0 = z.x - X0, y1 = z.y - X3;
        X0 += kp[0] * y0 + kp[6]  * y1;
        X1 += kp[1] * y0 + kp[7]  * y1;
        X2 += kp[2] * y0 + kp[8]  * y1;
        X3 += kp[3] * y0 + kp[9]  * y1;
        X4 += kp[4] * y0 + kp[10] * y1;
        X5 += kp[5] * y0 + kp[11] * y1;
    }

    // P becomes data-dependent only now; init from uniform post-history P
    float P[6][6];
    #pragma unroll
    for (int i = 0; i < 6; ++i) {
        #pragma unroll
        for (int j = 0; j < 6; ++j) P[i][j] = ws[180 + i * 6 + j];
    }

    // ---------------- prediction phase ----------------
    #pragma unroll 1
    for (int tp = 0; tp < len_pred; ++tp) {
        lstm_step();
        float c0 = 0.0f, c1 = 0.0f, c2 = 0.0f, c3 = 0.0f;
        #pragma unroll
        for (int blk = 0; blk < 2; ++blk)
            #pragma unroll
            for (int r = 0; r < 4; ++r) {
                int f = 16 * blk + 4 * s + r;
                f32x4 w = *(const f32x4*)&coT[f * 4];
                float hk = hn[4 * blk + r];
                c0 += w[0] * hk;
                c1 += w[1] * hk;
                c2 += w[2] * hk;
                c3 += w[3] * hk;
            }
        c0 += __shfl_xor(c0, 16, 64); c0 += __shfl_xor(c0, 32, 64);
        c1 += __shfl_xor(c1, 16, 64); c1 += __shfl_xor(c1, 32, 64);
        c2 += __shfl_xor(c2, 16, 64); c2 += __shfl_xor(c2, 32, 64);
        c3 += __shfl_xor(c3, 16, 64); c3 += __shfl_xor(c3, 32, 64);
        float cmd0 = c0 + cob[0], cmd1 = c1 + cob[1];
        float cmd2 = c2 + cob[2], cmd3 = c3 + cob[3];

        X0 = X0 + dt * X1 + hd * X2 + g0 * cmd0;
        X1 = X1 + dt * X2 + g1 * cmd0;
        X2 = X2 + g2 * cmd0;
        X3 = X3 + dt * X4 + hd * X5 + g0 * cmd1;
        X4 = X4 + dt * X5 + g1 * cmd1;
        X5 = X5 + g2 * cmd1;
        float Gs[6] = {ga0 * cmd2, ga1 * cmd2, ga2 * cmd2,
                       gb3 * cmd3, gb4 * cmd3, gb5 * cmd3};
        fpft(P);
        #pragma unroll
        for (int i = 0; i < 6; ++i)
            #pragma unroll
            for (int j = 0; j < 6; ++j)
                P[i][j] += Gs[i] * Gs[j];

        // epilogue stays precise (feeds outputs directly; ~1% of cost)
        float sx = sqrtf(P[0][0]), sy = sqrtf(P[3][3]);
        float rho = (P[0][3] + P[3][0]) / (2.0f * sx * sy);
        if (s == 0) {
            size_t o = ((size_t)tp * B + b) * 5u;
            out[o + 0] = X0;
            out[o + 1] = X3;
            out[o + 2] = sx;
            out[o + 3] = sy;
            out[o + 4] = rho;
        }
    }
}

extern "C" void kernel_launch(void* const* d_in, const int* in_sizes, int n_in,
                              void* d_out, int out_size, void* d_ws, size_t ws_size,
                              hipStream_t stream) {
    const int T = 16;
    const int B = in_sizes[0] / (2 * T);      // 32768
    const int len_pred = out_size / (5 * B);  // 25
    float* ws = (float*)d_ws;

    kf_precomp<<<1, 64, 0, stream>>>(
        (const float*)d_in[1], (const float*)d_in[2], (const float*)d_in[3],
        (const float*)d_in[4], (const float*)d_in[5], (const float*)d_in[6],
        (const float*)d_in[7], (const float*)d_in[8], (const float*)d_in[9], ws);

    const int grid = (B + EPB - 1) / EPB;     // one wave per 16 elements
    kalman_lstm<<<grid, BLK, 0, stream>>>(
        (const float*)d_in[0],  (const float*)d_in[8],
        (const float*)d_in[10], (const float*)d_in[11],
        (const float*)d_in[12], (const float*)d_in[13], (const float*)d_in[14],
        (const float*)d_in[15], (const float*)d_in[16], (const float*)d_in[17],
        ws, (float*)d_out, B, len_pred);
}